// Round 4
// baseline (157.986 us; speedup 1.0000x reference)
//
#include <hip/hip_runtime.h>

#define VOCAB 32000
#define PDIM  128
#define BDIM  64
#define LDIM  4096

typedef float vfloat4 __attribute__((ext_vector_type(4)));
typedef unsigned int uint32;
typedef unsigned short ushort16_t;

// fp32 -> bf16 round-to-nearest-even (inputs are finite normals; no NaN path)
__device__ __forceinline__ ushort16_t f2bf(float f) {
    uint32 u = __builtin_bit_cast(uint32, f);
    u = (u + 0x7FFFu + ((u >> 16) & 1u)) >> 16;
    return (ushort16_t)u;
}
// bf16 -> fp32 (exact)
__device__ __forceinline__ float bf2f(ushort16_t h) {
    return __builtin_bit_cast(float, (uint32)h << 16);
}

// ---------------------------------------------------------------------------
// Pass 1 (unchanged, proven): transpose + downcast w_in (P=128, V=32000) fp32
// -> w_t (V, P) bf16. Table 16.4 MB -> 8.2 MB, L2/L3-resident for the gather.
// ---------------------------------------------------------------------------
__global__ __launch_bounds__(256) void wt_transpose_kernel(
    const float* __restrict__ w_in, ushort16_t* __restrict__ w_t) {
    __shared__ float tile[128][65];
    const int v0 = blockIdx.x * 64;
    const int t  = threadIdx.x;

    #pragma unroll
    for (int i = 0; i < (128 * 64) / 256; ++i) {
        int idx = i * 256 + t;
        int p = idx >> 6;
        int c = idx & 63;
        tile[p][c] = w_in[(size_t)p * VOCAB + v0 + c];
    }
    __syncthreads();

    #pragma unroll
    for (int i = 0; i < (64 * 64) / 256; ++i) {
        int idx = i * 256 + t;
        int r  = idx >> 6;        // local v
        int pp = (idx & 63) * 2;  // p pair
        uint32 lo = (uint32)f2bf(tile[pp + 0][r]);
        uint32 hi = (uint32)f2bf(tile[pp + 1][r]);
        ((uint32*)w_t)[(size_t)(v0 + r) * (PDIM / 2) + (pp >> 1)] = lo | (hi << 16);
    }
}

// ---------------------------------------------------------------------------
// Pass 2 (v3, grid-fixed): block = (b, 32-p slice, 256-token chunk).
//  Each wave-store is 64 lanes x float4 = 1 KB FULLY CONTIGUOUS along l of a
//  single p-row -> one DRAM page per store instruction (previous variants
//  scattered each wave-store across 4-8 16KB-strided rows -> ~0% page-hit,
//  writes sank at ~2 TB/s vs 6.4 TB/s sequential fill).
//  Phase 1: gather 256 token rows x 64 B slice (8 lanes x ushort4 per row,
//    coalesced 64 B segments) -> p-major LDS tile [32][260] (row = 1040 B,
//    16 B-aligned for b128; phase-1 scatter writes <=4-way conflict, minor).
//  Phase 2: 8 passes; wave w stores p_local = pass*4+w as one 1 KB burst.
//  Grid 4096 = 64 b x 4 ps x 16 chunks, chunk fastest -> concurrent sibling
//  blocks extend the SAME 32 rows -> near-sequential 512 KB region coverage.
//  Per-block output = 32p x 256l = 8192 elems -> blocks = B*P*L/8192 = 4096.
//  (Round-3 failure was launching 1024 here: batches 16-63 never written.)
//  LDS 34.3 KB -> 4 blocks/CU (16 waves).
// ---------------------------------------------------------------------------
__global__ __launch_bounds__(256) void encoder_gather_kernel(
    const int* __restrict__ x, const ushort16_t* __restrict__ w_t,
    float* __restrict__ out) {
    __shared__ float tile[32][260];
    __shared__ int   sidx[256];

    const int t  = threadIdx.x;
    const int g  = blockIdx.x;            // 4096 = 64 b x 4 ps x 16 c
    const int c  = g & 15;                // l-chunk (fastest: row continuity)
    const int ps = (g >> 4) & 3;          // p-slice
    const int b  = g >> 6;
    const int l0 = c << 8;                // 256-token chunk base
    const int p0 = ps << 5;               // 32-p slice base

    sidx[t] = x[b * LDIM + l0 + t];
    __syncthreads();

    // Phase 1: 8 passes x 32 token rows; 8 lanes x ushort4 (8 B) per row.
    const int poff = (t & 7) * 4;
    #pragma unroll
    for (int pp = 0; pp < 8; ++pp) {
        int r = pp * 32 + (t >> 3);
        ushort4 v = *(const ushort4*)(w_t + (size_t)sidx[r] * PDIM + p0 + poff);
        tile[poff + 0][r] = bf2f(v.x);
        tile[poff + 1][r] = bf2f(v.y);
        tile[poff + 2][r] = bf2f(v.z);
        tile[poff + 3][r] = bf2f(v.w);
    }
    __syncthreads();

    // Phase 2: 8 passes; wave w owns p_local = pass*4 + w.
    // ds_read_b128 conflict-free (8-lane groups sweep all 32 banks);
    // store = 1 KB contiguous per wave instruction.
    const int w    = t >> 6;
    const int lane = t & 63;
    float* ob = out + (size_t)b * PDIM * LDIM + (size_t)p0 * LDIM + l0 + lane * 4;
    #pragma unroll
    for (int pass = 0; pass < 8; ++pass) {
        int pl = pass * 4 + w;
        vfloat4 s = *(const vfloat4*)&tile[pl][lane * 4];
        *(vfloat4*)(ob + (size_t)pl * LDIM) = s;
    }
}

// ---------------------------------------------------------------------------
// Fallback (only if d_ws can't hold the 8.2 MB bf16 transposed table):
// direct strided fp32 gather (bit-exact, slow).
// ---------------------------------------------------------------------------
__global__ __launch_bounds__(256) void encoder_direct_kernel(
    const int* __restrict__ x, const float* __restrict__ w_in,
    float* __restrict__ out) {
    const int g = blockIdx.x * 256 + threadIdx.x;
    const int b = g >> 12;
    const int l = g & 4095;
    const int idx = x[b * LDIM + l];
    const float* src = w_in + idx;
    float* dst = out + (size_t)b * PDIM * LDIM + l;
    #pragma unroll 4
    for (int p = 0; p < PDIM; ++p) {
        dst[(size_t)p * LDIM] = src[(size_t)p * VOCAB];
    }
}

extern "C" void kernel_launch(void* const* d_in, const int* in_sizes, int n_in,
                              void* d_out, int out_size, void* d_ws, size_t ws_size,
                              hipStream_t stream) {
    const int*   x    = (const int*)d_in[0];
    const float* w_in = (const float*)d_in[1];
    float*       out  = (float*)d_out;

    const size_t wt_bytes = (size_t)VOCAB * PDIM * sizeof(ushort16_t);
    if (ws_size >= wt_bytes) {
        ushort16_t* w_t = (ushort16_t*)d_ws;
        wt_transpose_kernel<<<VOCAB / 64, 256, 0, stream>>>(w_in, w_t);
        // blocks = B * (L/256) * (P/32) = 64 * 16 * 4 = 4096
        encoder_gather_kernel<<<BDIM * (LDIM / 256) * (PDIM / 32), 256, 0, stream>>>(x, w_t, out);
    } else {
        encoder_direct_kernel<<<(BDIM * LDIM) / 256, 256, 0, stream>>>(x, w_in, out);
    }
}